// Round 10
// baseline (774.920 us; speedup 1.0000x reference)
//
#include <hip/hip_runtime.h>

#define NN 50000
#define MPAD 50048   // 391 * 128
#define ICH 256
#define HID 64
#define HEADS 4
#define OCH 40
#define NE 800000
#define ETOT (NE + NN)
#define SLOPE 0.2f
#define LDP 40       // padded LDS row stride (bf16 elems): 32 data + 8 pad
#define CB (MPAD / 8)   // x->bf16 cast blocks: 256 thr x 8 elems
#define ZLD 264      // LDS row stride for the z tile (256 + 8 pad)
#define DSTR 64      // fixed CSR stride per dst (max degree ~40 << 64)
#define RNG 16       // dst-range hist blocks (LDS histogram, no global atomics)
#define DRNG (NN / RNG)  // 3125 dsts per range; counters 12.5 KB <= Bs 20.5 KB

typedef __bf16 v8bf __attribute__((ext_vector_type(8)));
typedef float v4f __attribute__((ext_vector_type(4)));

// ---- prep: [0,384) transpose W1/W2 to bf16; [384, +CB) cast x -> bf16
//      (pad rows zeroed). deg is produced by the hist blocks now. ----------
__global__ __launch_bounds__(256) void prep_kernel(
        const float* __restrict__ W1, const float* __restrict__ W2,
        __bf16* __restrict__ W1T, __bf16* __restrict__ W2T,
        const float* __restrict__ X, __bf16* __restrict__ Xb) {
    int blk = blockIdx.x;
    if (blk < 384) {
        int i = blk * 256 + threadIdx.x;  // 0..98303
        if (i < 65536) {
            int n = i >> 8, k = i & 255;
            W1T[n * 256 + k] = (__bf16)W1[k * 256 + n];
        } else {
            int j = i - 65536;  // 0..32767
            int n = j >> 8, k = j & 255;
            W2T[n * 256 + k] = (n < OCH) ? (__bf16)W2[k * OCH + n] : (__bf16)0.f;
        }
    } else {
        long j = blk - 384;                              // 0..CB-1
        long base = (j * 256 + threadIdx.x) * 8;         // elem index
        long row = base >> 8;
        int col = (int)(base & 255);
        union { __bf16 hh[8]; uint4 u; } pk;
        if (row < NN) {
            const float4* p = (const float4*)(X + row * ICH + col);
            float4 f0 = p[0], f1 = p[1];
            pk.hh[0] = (__bf16)f0.x; pk.hh[1] = (__bf16)f0.y;
            pk.hh[2] = (__bf16)f0.z; pk.hh[3] = (__bf16)f0.w;
            pk.hh[4] = (__bf16)f1.x; pk.hh[5] = (__bf16)f1.y;
            pk.hh[6] = (__bf16)f1.z; pk.hh[7] = (__bf16)f1.w;
        } else {
            pk.u = uint4{0u, 0u, 0u, 0u};
        }
        *(uint4*)(Xb + row * ICH + col) = pk.u;
    }
}

// ---- merged: blocks [0,RNG) range-partitioned LDS histogram + CSR build;
//      blocks [RNG, RNG+391) layer-1 GEMM (128x256 tiles, 8 waves, al1).
//      Hist block b exclusively owns dsts [b*DRNG, (b+1)*DRNG): streams the
//      dst list (vec4), counts in LDS (reusing Bs), writes csr slots for
//      in-range edges, appends self-loops, flushes deg coalesced. No global
//      atomics anywhere. Both halves depend only on prep. -------------------
__global__ __launch_bounds__(512) void hist_gemm1(
        const int* __restrict__ srcArr, const int* __restrict__ dstArr,
        int* __restrict__ deg, int* __restrict__ csr,
        const __bf16* __restrict__ Xb, const __bf16* __restrict__ B,
        __bf16* __restrict__ C, const float* __restrict__ a_s,
        const float* __restrict__ a_d, float* __restrict__ alsrc,
        float* __restrict__ aldst) {
    __shared__ __bf16 As[128 * LDP];
    __shared__ __bf16 Bs[256 * LDP];
    int tid = threadIdx.x;
    if (blockIdx.x < RNG) {  // ---- LDS histogram over an exclusive dst range
        int* cnt = (int*)Bs;               // 3125 counters, 12.5 KB
        int base = blockIdx.x * DRNG;
        for (int j = tid; j < DRNG; j += 512) cnt[j] = 0;
        __syncthreads();
        const int4* dst4 = (const int4*)dstArr;   // NE % 4 == 0
        for (int i4 = tid; i4 < NE / 4; i4 += 512) {
            int4 dv = dst4[i4];
#pragma unroll
            for (int k = 0; k < 4; k++) {
                int d = (&dv.x)[k];
                unsigned off = (unsigned)(d - base);
                if (off < DRNG) {
                    int s = srcArr[i4 * 4 + k];
                    int r = atomicAdd(&cnt[off], 1);   // LDS atomic (fast)
                    if (r < DSTR) csr[(d << 6) + r] = s;
                }
            }
        }
        __syncthreads();
        // self-loops (one per dst, appended last) + deg flush
        for (int j = tid; j < DRNG; j += 512) {
            int d = base + j;
            int r = cnt[j];
            if (r < DSTR) csr[(d << 6) + r] = d;
            deg[d] = r + 1;
        }
        return;
    }
    int blk = blockIdx.x - RNG;
    int lane = tid & 63, wid = tid >> 6;       // 8 waves
    int quad = lane >> 4, l15 = lane & 15;
    int wr = wid >> 2, wc = wid & 3;
    int am = wr * 64;                          // wave row-block within tile
    int wn = wc * 64;                          // wave col-block (one head)
    long row0 = (long)blk * 128;
    v4f acc[4][4] = {};
    for (int k0 = 0; k0 < 256; k0 += 32) {
        {   // stage A: 128 rows x 32 k, one uint4 per thread
            int r = tid >> 2, q = tid & 3;
            *(uint4*)(&As[r * LDP + q * 8]) =
                *(const uint4*)(Xb + (row0 + r) * ICH + k0 + q * 8);
        }
#pragma unroll
        for (int t = 0; t < 2; t++) {  // stage B: 256 cols x 32 k
            int i = tid + t * 512;
            int r = i >> 2, q = i & 3;
            *(uint4*)(&Bs[r * LDP + q * 8]) = *(const uint4*)(B + (size_t)r * 256 + k0 + q * 8);
        }
        __syncthreads();
        v8bf af[4], bfr[4];
#pragma unroll
        for (int t = 0; t < 4; t++) {
            af[t]  = *(const v8bf*)(&As[(am + t * 16 + l15) * LDP + quad * 8]);
            bfr[t] = *(const v8bf*)(&Bs[(wn + t * 16 + l15) * LDP + quad * 8]);
        }
#pragma unroll
        for (int mi = 0; mi < 4; mi++)
#pragma unroll
            for (int ni = 0; ni < 4; ni++)
                acc[mi][ni] = __builtin_amdgcn_mfma_f32_16x16x32_bf16(af[mi], bfr[ni], acc[mi][ni], 0, 0, 0);
        __syncthreads();
    }
    // C write
#pragma unroll
    for (int mi = 0; mi < 4; mi++)
#pragma unroll
        for (int ni = 0; ni < 4; ni++)
#pragma unroll
            for (int r = 0; r < 4; r++) {
                long row = row0 + am + mi * 16 + quad * 4 + r;
                C[row * ICH + wn + ni * 16 + l15] = (__bf16)acc[mi][ni][r];
            }
    // fused al1: this wave's 64 cols are exactly one head
    int head = wc;
    float asv[4], adv[4];
#pragma unroll
    for (int ni = 0; ni < 4; ni++) {
        int cc = wn + ni * 16 + l15;
        asv[ni] = a_s[cc];
        adv[ni] = a_d[cc];
    }
#pragma unroll
    for (int mi = 0; mi < 4; mi++)
#pragma unroll
        for (int r = 0; r < 4; r++) {
            float vs = 0.f, vd = 0.f;
#pragma unroll
            for (int ni = 0; ni < 4; ni++) {
                vs += acc[mi][ni][r] * asv[ni];
                vd += acc[mi][ni][r] * adv[ni];
            }
#pragma unroll
            for (int m = 1; m <= 8; m <<= 1) {
                vs += __shfl_xor(vs, m, 64);
                vd += __shfl_xor(vd, m, 64);
            }
            long row = row0 + am + mi * 16 + quad * 4 + r;
            if (l15 == 0 && row < NN) {
                alsrc[row * HEADS + head] = vs;
                aldst[row * HEADS + head] = vd;
            }
        }
}

// -------- layer-1 aggregation + fused layer-2 GEMM + al2 epilogue ---------
//   8 waves / 8 dsts per block (512 thr); wave-0 MFMA epilogue serves 8 dsts.
//   Gather body = proven structure (wave/dst; 2 edge-slots x 32 cg).
//   Zs rows 0..7 = z-rows, rows 8..15 zeroed (disjoint -> one barrier).
__global__ __launch_bounds__(512) void agg1_gemm2(
        const int* __restrict__ deg, const int* __restrict__ csr,
        const __bf16* __restrict__ h, const float* __restrict__ alsrc,
        const float* __restrict__ aldst, const float* __restrict__ bias,
        const __bf16* __restrict__ W2T, const float* __restrict__ a_s2,
        const float* __restrict__ a_d2, __bf16* __restrict__ h2,
        float* __restrict__ alsrc2, float* __restrict__ aldst2) {
    __shared__ __bf16 Zs[16 * ZLD];
    int tid = threadIdx.x;
    int lane = tid & 63, wid = tid >> 6;
    int d = blockIdx.x * 8 + wid;           // grid = NN/8 exact; d < NN always
    // zero rows 8..15 only (rows 0..7 are fully written by the 8 waves)
    {
        uint4* zp = (uint4*)(&Zs[8 * ZLD]);
        for (int i = tid; i < 8 * ZLD / 8; i += 512) zp[i] = uint4{0u, 0u, 0u, 0u};
    }
    int es = lane >> 5;
    int cg = lane & 31;
    int head = cg >> 3;
    int dg = deg[d]; if (dg > DSTR) dg = DSTR;
    int e0 = d << 6, e1 = e0 + dg;
    float ald = aldst[d * HEADS + head];
    float acc[8] = {};
    float wsum = 0.f;
    int e = e0 + es;
    int sA = (e < e1) ? csr[e] : 0;
    float alA = alsrc[sA * HEADS + head];
    v8bf hvA = *(const v8bf*)(h + (size_t)sA * ICH + cg * 8);
    for (; e < e1; e += 2) {
        int en = e + 2;
        int sB = (en < e1) ? csr[en] : 0;
        float alB = alsrc[sB * HEADS + head];
        v8bf hvB = *(const v8bf*)(h + (size_t)sB * ICH + cg * 8);
        float x = alA + ald;
        x = (x > 0.f) ? x : SLOPE * x;
        float w = __expf(x);
        wsum += w;
#pragma unroll
        for (int j = 0; j < 8; j++) acc[j] += w * (float)hvA[j];
        alA = alB; hvA = hvB;
    }
#pragma unroll
    for (int j = 0; j < 8; j++) acc[j] += __shfl_down(acc[j], 32, 64);
    wsum += __shfl_down(wsum, 32, 64);
    if (es == 0) {
        float inv = 1.f / (wsum + 1e-16f);
        union { __bf16 hh[8]; uint4 u; } p;
#pragma unroll
        for (int j = 0; j < 8; j++) {
            float o = acc[j] * inv + bias[cg * 8 + j];
            o = (o > 0.f) ? o : (__expf(o) - 1.f);  // ELU
            p.hh[j] = (__bf16)o;
        }
        *(uint4*)(&Zs[wid * ZLD + cg * 8]) = p.u;   // z-row -> LDS (no global z)
    }
    __syncthreads();
    if (wid == 0) {   // layer-2 GEMM epilogue: h2[8x40] = z(8x256) @ W2T
        int quad = lane >> 4, l15 = lane & 15;
        v4f acc2[3] = {};  // col groups 0..2 cover cols 0..47 (W2T rows 40..47 = 0)
        for (int k0 = 0; k0 < 256; k0 += 32) {
            v8bf af = *(const v8bf*)(&Zs[l15 * ZLD + k0 + quad * 8]);
#pragma unroll
            for (int g = 0; g < 3; g++) {
                v8bf bfr = *(const v8bf*)(W2T + (size_t)(g * 16 + l15) * 256 + k0 + quad * 8);
                acc2[g] = __builtin_amdgcn_mfma_f32_16x16x32_bf16(af, bfr, acc2[g], 0, 0, 0);
            }
        }
        // C layout: row = quad*4 + r, col = g*16 + l15 -> rows 0..7 in quads 0,1
        if (quad < 2) {
            float asv[3], adv[3];
#pragma unroll
            for (int g = 0; g < 3; g++) {
                int c = g * 16 + l15;
                bool on = c < OCH;
                asv[g] = on ? a_s2[c] : 0.f;
                adv[g] = on ? a_d2[c] : 0.f;
            }
#pragma unroll
            for (int r = 0; r < 4; r++) {
                long drow = (long)blockIdx.x * 8 + quad * 4 + r;
#pragma unroll
                for (int g = 0; g < 3; g++) {
                    int c = g * 16 + l15;
                    if (c < OCH) h2[drow * OCH + c] = (__bf16)acc2[g][r];
                }
                float vs = 0.f, vd = 0.f;
#pragma unroll
                for (int g = 0; g < 3; g++) {
                    vs += acc2[g][r] * asv[g];
                    vd += acc2[g][r] * adv[g];
                }
#pragma unroll
                for (int m = 1; m <= 8; m <<= 1) {  // reduce over l15 (within quad, all active)
                    vs += __shfl_xor(vs, m, 64);
                    vd += __shfl_xor(vd, m, 64);
                }
                if (l15 == 0) {
                    alsrc2[drow] = vs;
                    aldst2[drow] = vd;
                }
            }
        }
    }
}

// -------- layer-2 aggregation (proven body): wave/dst; 8 edge-slots x 8 cg;
//          compact h2; fixed-stride CSR -------------------------------------
__global__ __launch_bounds__(256) void aggregate2(
        const int* __restrict__ deg, const int* __restrict__ csr,
        const __bf16* __restrict__ h2, const float* __restrict__ alsrc,
        const float* __restrict__ aldst, const float* __restrict__ bias,
        float* __restrict__ out) {
    int lane = threadIdx.x & 63, wid = threadIdx.x >> 6;
    int d = blockIdx.x * 4 + wid;
    if (d >= NN) return;
    int es = lane >> 3;
    int cg = lane & 7;
    bool on = cg < 5;
    int cgc = on ? cg : 4;
    int dg = deg[d]; if (dg > DSTR) dg = DSTR;
    int e0 = d << 6, e1 = e0 + dg;
    float ald = aldst[d];
    float acc[8] = {};
    float wsum = 0.f;
    int e = e0 + es;
    int sA = (e < e1) ? csr[e] : 0;
    float alA = alsrc[sA];
    v8bf hvA = *(const v8bf*)(h2 + (size_t)sA * OCH + cgc * 8);
    for (; e < e1; e += 8) {
        int en = e + 8;
        int sB = (en < e1) ? csr[en] : 0;
        float alB = alsrc[sB];
        v8bf hvB = *(const v8bf*)(h2 + (size_t)sB * OCH + cgc * 8);
        float x = alA + ald;
        x = (x > 0.f) ? x : SLOPE * x;
        float w = __expf(x);
        wsum += w;
#pragma unroll
        for (int j = 0; j < 8; j++) acc[j] += w * (float)hvA[j];
        alA = alB; hvA = hvB;
    }
#pragma unroll
    for (int m = 8; m <= 32; m <<= 1) {
#pragma unroll
        for (int j = 0; j < 8; j++) acc[j] += __shfl_xor(acc[j], m, 64);
        wsum += __shfl_xor(wsum, m, 64);
    }
    if (es == 0 && on) {
        float inv = 1.f / (wsum + 1e-16f);
#pragma unroll
        for (int j = 0; j < 8; j++)
            out[(size_t)d * OCH + cg * 8 + j] = acc[j] * inv + bias[cg * 8 + j];
    }
}

extern "C" void kernel_launch(void* const* d_in, const int* in_sizes, int n_in,
                              void* d_out, int out_size, void* d_ws, size_t ws_size,
                              hipStream_t stream) {
    const float* x   = (const float*)d_in[0];
    const int*   ei  = (const int*)d_in[1];
    const float* W1  = (const float*)d_in[2];
    const float* as1 = (const float*)d_in[3];
    const float* ad1 = (const float*)d_in[4];
    const float* b1  = (const float*)d_in[5];
    const float* W2  = (const float*)d_in[6];
    const float* as2 = (const float*)d_in[7];
    const float* ad2 = (const float*)d_in[8];
    const float* b2  = (const float*)d_in[9];
    float* out = (float*)d_out;

    char* ws = (char*)d_ws;
    size_t o = 0;
    auto alloc = [&](size_t bytes) {
        void* p = ws + o;
        o += (bytes + 255) & ~(size_t)255;
        return p;
    };
    __bf16* h1    = (__bf16*)alloc((size_t)MPAD * ICH * 2);
    __bf16* xbf   = (__bf16*)alloc((size_t)MPAD * ICH * 2);
    __bf16* h2    = (__bf16*)alloc((size_t)MPAD * OCH * 2);
    __bf16* W1T   = (__bf16*)alloc((size_t)256 * 256 * 2);
    __bf16* W2T   = (__bf16*)alloc((size_t)128 * 256 * 2);
    float* alsrc1 = (float*)alloc((size_t)NN * HEADS * 4);
    float* aldst1 = (float*)alloc((size_t)NN * HEADS * 4);
    float* alsrc2 = (float*)alloc((size_t)NN * 4);
    float* aldst2 = (float*)alloc((size_t)NN * 4);
    int*   deg    = (int*)alloc((size_t)NN * 4);
    int*   csr    = (int*)alloc((size_t)NN * DSTR * 4);

    const int* srcArr = ei;
    const int* dstArr = ei + NE;

    // prep: transW || x-cast (deg now produced by hist blocks; no memset)
    prep_kernel<<<384 + CB, 256, 0, stream>>>(W1, W2, W1T, W2T, x, xbf);

    // merged: range-partitioned LDS hist + CSR || layer-1 GEMM (al1 fused)
    hist_gemm1<<<RNG + MPAD / 128, 512, 0, stream>>>(
        srcArr, dstArr, deg, csr,
        xbf, W1T, h1, as1, ad1, alsrc1, aldst1);

    // layer-1 aggregation + wave-0 layer-2 GEMM (8 dsts/block; z stays in LDS)
    agg1_gemm2<<<NN / 8, 512, 0, stream>>>(deg, csr, h1, alsrc1, aldst1, b1,
                                           W2T, as2, ad2, h2, alsrc2, aldst2);

    aggregate2<<<NN / 4, 256, 0, stream>>>(deg, csr, h2, alsrc2, aldst2, b2, out);
}

// Round 11
// 256.661 us; speedup vs baseline: 3.0192x; 3.0192x over previous
//
#include <hip/hip_runtime.h>

#define NN 50000
#define MPAD 50048   // 391 * 128
#define ICH 256
#define HID 64
#define HEADS 4
#define OCH 40
#define NE 800000
#define ETOT (NE + NN)
#define SLOPE 0.2f
#define LDP 40       // padded LDS row stride (bf16 elems): 32 data + 8 pad
#define ZB 49        // deg-zero blocks: 49 * 256 * 4 ints >= 50000
#define ZLD 264      // LDS row stride for the z tile (256 + 8 pad)
#define DSTR 64      // fixed CSR stride per dst (max degree ~40 << 64)
#define EPT 8        // edges per thread in hist
#define HBG ((ETOT + 4095) / 4096)  // hist blocks in merged kernel (512 thr x 8)

typedef __bf16 v8bf __attribute__((ext_vector_type(8)));
typedef float v4f __attribute__((ext_vector_type(4)));

// ---- prep: [0,384) transpose W1/W2 to bf16; [384,384+ZB) zero deg.
//      (x-cast folded into gemm1's A-staging; xbf buffer eliminated.)
__global__ __launch_bounds__(256) void prep_kernel(
        const float* __restrict__ W1, const float* __restrict__ W2,
        __bf16* __restrict__ W1T, __bf16* __restrict__ W2T,
        int* __restrict__ deg) {
    int blk = blockIdx.x;
    if (blk < 384) {
        int i = blk * 256 + threadIdx.x;  // 0..98303
        if (i < 65536) {
            int n = i >> 8, k = i & 255;
            W1T[n * 256 + k] = (__bf16)W1[k * 256 + n];
        } else {
            int j = i - 65536;  // 0..32767
            int n = j >> 8, k = j & 255;
            W2T[n * 256 + k] = (n < OCH) ? (__bf16)W2[k * OCH + n] : (__bf16)0.f;
        }
    } else {
        int i = (blk - 384) * 256 + threadIdx.x;   // uint4 index
        if (i < (NN + 3) / 4) ((uint4*)deg)[i] = uint4{0u, 0u, 0u, 0u};
    }
}

// ---- merged: blocks [0,HBG) hist+direct-CSR (global atomics, EPT=8);
//      blocks [HBG, HBG+391) layer-1 GEMM (128x256 tiles, 8 waves, al1;
//      A staged directly from fp32 X with in-register bf16 cvt — hidden
//      under the hist's ~80us RMW-throughput cap).
//      Both depend only on prep; agg1 needs both -> safe task parallelism. --
__global__ __launch_bounds__(512) void hist_gemm1(
        const int* __restrict__ srcArr, const int* __restrict__ dstArr,
        int* __restrict__ deg, int* __restrict__ csr,
        const float* __restrict__ X, const __bf16* __restrict__ B,
        __bf16* __restrict__ C, const float* __restrict__ a_s,
        const float* __restrict__ a_d, float* __restrict__ alsrc,
        float* __restrict__ aldst) {
    __shared__ __bf16 As[128 * LDP];
    __shared__ __bf16 Bs[256 * LDP];
    if (blockIdx.x < HBG) {  // ---- hist + CSR scatter, 8 edges/thread ------
        int i0 = blockIdx.x * (512 * EPT) + threadIdx.x;
        int dd[EPT], ss[EPT], rr[EPT];
        bool ok[EPT];
#pragma unroll
        for (int t = 0; t < EPT; t++) {
            int i = i0 + t * 512;
            ok[t] = i < ETOT;
            dd[t] = ss[t] = 0;
            if (ok[t]) {
                if (i < NE) { dd[t] = dstArr[i]; ss[t] = srcArr[i]; }
                else        { dd[t] = ss[t] = i - NE; }
            }
        }
#pragma unroll
        for (int t = 0; t < EPT; t++)
            if (ok[t]) rr[t] = atomicAdd(&deg[dd[t]], 1);   // independent RMWs
#pragma unroll
        for (int t = 0; t < EPT; t++)
            if (ok[t] && rr[t] < DSTR) csr[(dd[t] << 6) + rr[t]] = ss[t];
        return;
    }
    int blk = blockIdx.x - HBG;
    int tid = threadIdx.x;
    int lane = tid & 63, wid = tid >> 6;       // 8 waves
    int quad = lane >> 4, l15 = lane & 15;
    int wr = wid >> 2, wc = wid & 3;
    int am = wr * 64;                          // wave row-block within tile
    int wn = wc * 64;                          // wave col-block (one head)
    long row0 = (long)blk * 128;
    v4f acc[4][4] = {};
    for (int k0 = 0; k0 < 256; k0 += 32) {
        {   // stage A: 128 rows x 32 k, fp32 -> bf16 in-register, one uint4/thr
            int r = tid >> 2, q = tid & 3;
            long row = row0 + r;
            union { __bf16 hh[8]; uint4 u; } pk;
            if (row < NN) {
                const float4* p = (const float4*)(X + row * ICH + k0 + q * 8);
                float4 f0 = p[0], f1 = p[1];
                pk.hh[0] = (__bf16)f0.x; pk.hh[1] = (__bf16)f0.y;
                pk.hh[2] = (__bf16)f0.z; pk.hh[3] = (__bf16)f0.w;
                pk.hh[4] = (__bf16)f1.x; pk.hh[5] = (__bf16)f1.y;
                pk.hh[6] = (__bf16)f1.z; pk.hh[7] = (__bf16)f1.w;
            } else {
                pk.u = uint4{0u, 0u, 0u, 0u};
            }
            *(uint4*)(&As[r * LDP + q * 8]) = pk.u;
        }
#pragma unroll
        for (int t = 0; t < 2; t++) {  // stage B: 256 cols x 32 k
            int i = tid + t * 512;
            int r = i >> 2, q = i & 3;
            *(uint4*)(&Bs[r * LDP + q * 8]) = *(const uint4*)(B + (size_t)r * 256 + k0 + q * 8);
        }
        __syncthreads();
        v8bf af[4], bfr[4];
#pragma unroll
        for (int t = 0; t < 4; t++) {
            af[t]  = *(const v8bf*)(&As[(am + t * 16 + l15) * LDP + quad * 8]);
            bfr[t] = *(const v8bf*)(&Bs[(wn + t * 16 + l15) * LDP + quad * 8]);
        }
#pragma unroll
        for (int mi = 0; mi < 4; mi++)
#pragma unroll
            for (int ni = 0; ni < 4; ni++)
                acc[mi][ni] = __builtin_amdgcn_mfma_f32_16x16x32_bf16(af[mi], bfr[ni], acc[mi][ni], 0, 0, 0);
        __syncthreads();
    }
    // C write
#pragma unroll
    for (int mi = 0; mi < 4; mi++)
#pragma unroll
        for (int ni = 0; ni < 4; ni++)
#pragma unroll
            for (int r = 0; r < 4; r++) {
                long row = row0 + am + mi * 16 + quad * 4 + r;
                C[row * ICH + wn + ni * 16 + l15] = (__bf16)acc[mi][ni][r];
            }
    // fused al1: this wave's 64 cols are exactly one head
    int head = wc;
    float asv[4], adv[4];
#pragma unroll
    for (int ni = 0; ni < 4; ni++) {
        int cc = wn + ni * 16 + l15;
        asv[ni] = a_s[cc];
        adv[ni] = a_d[cc];
    }
#pragma unroll
    for (int mi = 0; mi < 4; mi++)
#pragma unroll
        for (int r = 0; r < 4; r++) {
            float vs = 0.f, vd = 0.f;
#pragma unroll
            for (int ni = 0; ni < 4; ni++) {
                vs += acc[mi][ni][r] * asv[ni];
                vd += acc[mi][ni][r] * adv[ni];
            }
#pragma unroll
            for (int m = 1; m <= 8; m <<= 1) {
                vs += __shfl_xor(vs, m, 64);
                vd += __shfl_xor(vd, m, 64);
            }
            long row = row0 + am + mi * 16 + quad * 4 + r;
            if (l15 == 0 && row < NN) {
                alsrc[row * HEADS + head] = vs;
                aldst[row * HEADS + head] = vd;
            }
        }
}

// -------- layer-1 aggregation + fused layer-2 GEMM + al2 epilogue ---------
//   8 waves / 8 dsts per block (512 thr); wave-0 MFMA epilogue serves 8 dsts.
//   Gather body = proven structure (wave/dst; 2 edge-slots x 32 cg).
//   Zs rows 0..7 = z-rows, rows 8..15 zeroed (disjoint -> one barrier).
__global__ __launch_bounds__(512) void agg1_gemm2(
        const int* __restrict__ deg, const int* __restrict__ csr,
        const __bf16* __restrict__ h, const float* __restrict__ alsrc,
        const float* __restrict__ aldst, const float* __restrict__ bias,
        const __bf16* __restrict__ W2T, const float* __restrict__ a_s2,
        const float* __restrict__ a_d2, __bf16* __restrict__ h2,
        float* __restrict__ alsrc2, float* __restrict__ aldst2) {
    __shared__ __bf16 Zs[16 * ZLD];
    int tid = threadIdx.x;
    int lane = tid & 63, wid = tid >> 6;
    int d = blockIdx.x * 8 + wid;           // grid = NN/8 exact; d < NN always
    // zero rows 8..15 only (rows 0..7 are fully written by the 8 waves)
    {
        uint4* zp = (uint4*)(&Zs[8 * ZLD]);
        for (int i = tid; i < 8 * ZLD / 8; i += 512) zp[i] = uint4{0u, 0u, 0u, 0u};
    }
    int es = lane >> 5;
    int cg = lane & 31;
    int head = cg >> 3;
    int dg = deg[d]; if (dg > DSTR) dg = DSTR;
    int e0 = d << 6, e1 = e0 + dg;
    float ald = aldst[d * HEADS + head];
    float acc[8] = {};
    float wsum = 0.f;
    int e = e0 + es;
    int sA = (e < e1) ? csr[e] : 0;
    float alA = alsrc[sA * HEADS + head];
    v8bf hvA = *(const v8bf*)(h + (size_t)sA * ICH + cg * 8);
    for (; e < e1; e += 2) {
        int en = e + 2;
        int sB = (en < e1) ? csr[en] : 0;
        float alB = alsrc[sB * HEADS + head];
        v8bf hvB = *(const v8bf*)(h + (size_t)sB * ICH + cg * 8);
        float x = alA + ald;
        x = (x > 0.f) ? x : SLOPE * x;
        float w = __expf(x);
        wsum += w;
#pragma unroll
        for (int j = 0; j < 8; j++) acc[j] += w * (float)hvA[j];
        alA = alB; hvA = hvB;
    }
#pragma unroll
    for (int j = 0; j < 8; j++) acc[j] += __shfl_down(acc[j], 32, 64);
    wsum += __shfl_down(wsum, 32, 64);
    if (es == 0) {
        float inv = 1.f / (wsum + 1e-16f);
        union { __bf16 hh[8]; uint4 u; } p;
#pragma unroll
        for (int j = 0; j < 8; j++) {
            float o = acc[j] * inv + bias[cg * 8 + j];
            o = (o > 0.f) ? o : (__expf(o) - 1.f);  // ELU
            p.hh[j] = (__bf16)o;
        }
        *(uint4*)(&Zs[wid * ZLD + cg * 8]) = p.u;   // z-row -> LDS (no global z)
    }
    __syncthreads();
    if (wid == 0) {   // layer-2 GEMM epilogue: h2[8x40] = z(8x256) @ W2T
        int quad = lane >> 4, l15 = lane & 15;
        v4f acc2[3] = {};  // col groups 0..2 cover cols 0..47 (W2T rows 40..47 = 0)
        for (int k0 = 0; k0 < 256; k0 += 32) {
            v8bf af = *(const v8bf*)(&Zs[l15 * ZLD + k0 + quad * 8]);
#pragma unroll
            for (int g = 0; g < 3; g++) {
                v8bf bfr = *(const v8bf*)(W2T + (size_t)(g * 16 + l15) * 256 + k0 + quad * 8);
                acc2[g] = __builtin_amdgcn_mfma_f32_16x16x32_bf16(af, bfr, acc2[g], 0, 0, 0);
            }
        }
        // C layout: row = quad*4 + r, col = g*16 + l15 -> rows 0..7 in quads 0,1
        if (quad < 2) {
            float asv[3], adv[3];
#pragma unroll
            for (int g = 0; g < 3; g++) {
                int c = g * 16 + l15;
                bool on = c < OCH;
                asv[g] = on ? a_s2[c] : 0.f;
                adv[g] = on ? a_d2[c] : 0.f;
            }
#pragma unroll
            for (int r = 0; r < 4; r++) {
                long drow = (long)blockIdx.x * 8 + quad * 4 + r;
#pragma unroll
                for (int g = 0; g < 3; g++) {
                    int c = g * 16 + l15;
                    if (c < OCH) h2[drow * OCH + c] = (__bf16)acc2[g][r];
                }
                float vs = 0.f, vd = 0.f;
#pragma unroll
                for (int g = 0; g < 3; g++) {
                    vs += acc2[g][r] * asv[g];
                    vd += acc2[g][r] * adv[g];
                }
#pragma unroll
                for (int m = 1; m <= 8; m <<= 1) {  // reduce over l15 (within quad, all active)
                    vs += __shfl_xor(vs, m, 64);
                    vd += __shfl_xor(vd, m, 64);
                }
                if (l15 == 0) {
                    alsrc2[drow] = vs;
                    aldst2[drow] = vd;
                }
            }
        }
    }
}

// -------- layer-2 aggregation (proven body): wave/dst; 8 edge-slots x 8 cg;
//          compact h2; fixed-stride CSR -------------------------------------
__global__ __launch_bounds__(256) void aggregate2(
        const int* __restrict__ deg, const int* __restrict__ csr,
        const __bf16* __restrict__ h2, const float* __restrict__ alsrc,
        const float* __restrict__ aldst, const float* __restrict__ bias,
        float* __restrict__ out) {
    int lane = threadIdx.x & 63, wid = threadIdx.x >> 6;
    int d = blockIdx.x * 4 + wid;
    if (d >= NN) return;
    int es = lane >> 3;
    int cg = lane & 7;
    bool on = cg < 5;
    int cgc = on ? cg : 4;
    int dg = deg[d]; if (dg > DSTR) dg = DSTR;
    int e0 = d << 6, e1 = e0 + dg;
    float ald = aldst[d];
    float acc[8] = {};
    float wsum = 0.f;
    int e = e0 + es;
    int sA = (e < e1) ? csr[e] : 0;
    float alA = alsrc[sA];
    v8bf hvA = *(const v8bf*)(h2 + (size_t)sA * OCH + cgc * 8);
    for (; e < e1; e += 8) {
        int en = e + 8;
        int sB = (en < e1) ? csr[en] : 0;
        float alB = alsrc[sB];
        v8bf hvB = *(const v8bf*)(h2 + (size_t)sB * OCH + cgc * 8);
        float x = alA + ald;
        x = (x > 0.f) ? x : SLOPE * x;
        float w = __expf(x);
        wsum += w;
#pragma unroll
        for (int j = 0; j < 8; j++) acc[j] += w * (float)hvA[j];
        alA = alB; hvA = hvB;
    }
#pragma unroll
    for (int m = 8; m <= 32; m <<= 1) {
#pragma unroll
        for (int j = 0; j < 8; j++) acc[j] += __shfl_xor(acc[j], m, 64);
        wsum += __shfl_xor(wsum, m, 64);
    }
    if (es == 0 && on) {
        float inv = 1.f / (wsum + 1e-16f);
#pragma unroll
        for (int j = 0; j < 8; j++)
            out[(size_t)d * OCH + cg * 8 + j] = acc[j] * inv + bias[cg * 8 + j];
    }
}

extern "C" void kernel_launch(void* const* d_in, const int* in_sizes, int n_in,
                              void* d_out, int out_size, void* d_ws, size_t ws_size,
                              hipStream_t stream) {
    const float* x   = (const float*)d_in[0];
    const int*   ei  = (const int*)d_in[1];
    const float* W1  = (const float*)d_in[2];
    const float* as1 = (const float*)d_in[3];
    const float* ad1 = (const float*)d_in[4];
    const float* b1  = (const float*)d_in[5];
    const float* W2  = (const float*)d_in[6];
    const float* as2 = (const float*)d_in[7];
    const float* ad2 = (const float*)d_in[8];
    const float* b2  = (const float*)d_in[9];
    float* out = (float*)d_out;

    char* ws = (char*)d_ws;
    size_t o = 0;
    auto alloc = [&](size_t bytes) {
        void* p = ws + o;
        o += (bytes + 255) & ~(size_t)255;
        return p;
    };
    __bf16* h1    = (__bf16*)alloc((size_t)MPAD * ICH * 2);
    __bf16* h2    = (__bf16*)alloc((size_t)MPAD * OCH * 2);
    __bf16* W1T   = (__bf16*)alloc((size_t)256 * 256 * 2);
    __bf16* W2T   = (__bf16*)alloc((size_t)128 * 256 * 2);
    float* alsrc1 = (float*)alloc((size_t)NN * HEADS * 4);
    float* aldst1 = (float*)alloc((size_t)NN * HEADS * 4);
    float* alsrc2 = (float*)alloc((size_t)NN * 4);
    float* aldst2 = (float*)alloc((size_t)NN * 4);
    int*   deg    = (int*)alloc((size_t)NN * 4);
    int*   csr    = (int*)alloc((size_t)NN * DSTR * 4);

    const int* srcArr = ei;
    const int* dstArr = ei + NE;

    // prep: transW || deg-zero (x-cast now folded into gemm1's A staging)
    prep_kernel<<<384 + ZB, 256, 0, stream>>>(W1, W2, W1T, W2T, deg);

    // merged: hist+CSR (8-edge atomic MLP) || layer-1 GEMM (fp32 A, al1 fused)
    hist_gemm1<<<HBG + MPAD / 128, 512, 0, stream>>>(
        srcArr, dstArr, deg, csr,
        x, W1T, h1, as1, ad1, alsrc1, aldst1);

    // layer-1 aggregation + wave-0 layer-2 GEMM (8 dsts/block; z stays in LDS)
    agg1_gemm2<<<NN / 8, 512, 0, stream>>>(deg, csr, h1, alsrc1, aldst1, b1,
                                           W2T, as2, ad2, h2, alsrc2, aldst2);

    aggregate2<<<NN / 4, 256, 0, stream>>>(deg, csr, h2, alsrc2, aldst2, b2, out);
}